// Round 10
// baseline (457.258 us; speedup 1.0000x reference)
//
#include <hip/hip_runtime.h>
#include <hip/hip_bf16.h>
#include <stdint.h>

#define NN 65536
#define NE 1048576
#define E2 (NE + NN)      // edges + self loops = 1,114,112 = 8704*128
#define HID 128
#define LP 136            // padded LDS row pitch (fp16 elems) for node-kernel A tiles
#define RMAX 13           // max runs in LDS run-table (overflow -> global atomics)
#define TP 129            // run-table stride in words
#define TABW 1680         // ceil(RMAX*TP/4)*4 words
#define ENC_NEG 0x007FFFFFu   // encf(-inf)

typedef _Float16 h8v __attribute__((ext_vector_type(8)));
typedef __fp16 fp16x2 __attribute__((ext_vector_type(2)));
typedef __attribute__((ext_vector_type(4))) float f32x4;

__device__ __forceinline__ uint32_t pkh(float a, float b){
    union { fp16x2 h; uint32_t u; } v;
    v.h = __builtin_amdgcn_cvt_pkrtz(a, b);
    return v.u;
}
// monotone float->uint encoding for unsigned atomicMax (branchless)
__device__ __forceinline__ uint32_t encf(float x){
    union { float f; uint32_t u; } v; v.f = x;
    return v.u ^ (uint32_t)(((int32_t)v.u >> 31) | 0x80000000);
}
__device__ __forceinline__ float decf(uint32_t u){
    union { uint32_t u; float f; } v;
    v.u = u ^ (uint32_t)(~((int32_t)u >> 31) | 0x80000000);
    return v.f;
}

// direct global->LDS DMA, 16B per lane (dest = wave-uniform base + lane*16)
__device__ __forceinline__ void gl_lds16(const _Float16* g, _Float16* l){
    __builtin_amdgcn_global_load_lds(
        (const __attribute__((address_space(1))) uint32_t*)g,
        (__attribute__((address_space(3))) uint32_t*)l, 16, 0, 0);
}

// stage a 128x128 fp16 weight into LDS via DMA (4-wave version, k_edge):
// linear dest, inverse-XOR-swizzled per-lane global source.
__device__ __forceinline__ void dma_w(const _Float16* __restrict__ wT, _Float16* Ws,
                                      int wv, int lane){
    #pragma unroll
    for (int rnd = 0; rnd < 8; rnd++){
        int g = rnd*256 + wv*64 + lane;              // 16B chunk id 0..2047
        int r = g >> 4, kc = g & 15;
        gl_lds16(wT + r*HID + ((kc ^ (r & 15)) << 3),
                 Ws + rnd*2048 + wv*512);
    }
}
// 8-wave version (512-thread node kernels): same layout, 4 rounds.
__device__ __forceinline__ void dma_w8(const _Float16* __restrict__ wT, _Float16* Ws,
                                       int wv, int lane){
    #pragma unroll
    for (int rnd = 0; rnd < 4; rnd++){
        int g = rnd*512 + wv*64 + lane;              // 16B chunk id 0..2047
        int r = g >> 4, kc = g & 15;
        gl_lds16(wT + r*HID + ((kc ^ (r & 15)) << 3),
                 Ws + rnd*4096 + wv*512);
    }
}

// per-wave 16x128x128 fp16 GEMM slice: A rows wv*16..+15 from padded LDS tile,
// B from swizzled Ws. acc[ct] covers col ct*16+lq, rows quad*4+rg.
// R5 lesson: weights must be LDS-resident, not direct-global.
__device__ __forceinline__ void gemm_w(const _Float16* Ts, const _Float16* Ws,
                                       f32x4 (&acc)[8], int wv, int lq, int quad){
    #pragma unroll
    for (int k0 = 0; k0 < 128; k0 += 32){
        h8v af = *(const h8v*)(Ts + (wv*16 + lq)*LP + k0 + quad*8);
        const int kcb = k0 >> 3;
        #pragma unroll
        for (int ct = 0; ct < 8; ct++){
            h8v b = *(const h8v*)(Ws + (ct*16 + lq)*128 + (((kcb + quad) ^ lq) << 3));
            acc[ct] = __builtin_amdgcn_mfma_f32_16x16x32_f16(af, b, acc[ct], 0, 0, 0);
        }
    }
}

__device__ __forceinline__ void zero_acc8(f32x4 (&acc)[8]){
    #pragma unroll
    for (int b = 0; b < 8; b++) acc[b] = (f32x4){0.f, 0.f, 0.f, 0.f};
}

__device__ __forceinline__ void zero_acc(f32x4 (&acc)[2][8]){
    #pragma unroll
    for (int a = 0; a < 2; a++)
        #pragma unroll
        for (int b = 0; b < 8; b++)
            acc[a][b] = (f32x4){0.f, 0.f, 0.f, 0.f};
}

// ---------------- prep: weight transposes + cnt init + folded bias ----------------
// Coalesced transpose (R9): float4 row reads -> LDS transpose -> uint4 writes.
struct WT { const float* s[10]; _Float16* d[10]; };
__global__ void k_prep(WT w, uint32_t* cnt,
                       const float* lb2_0, const float* gw1_0, const float* gb1_0,
                       const float* lb2_1, const float* gw1_1, const float* gb1_1,
                       float* c1p){
    int b = blockIdx.x;
    int t = threadIdx.x;
    if (b < 10){
        __shared__ _Float16 T[128*136];
        const float* src = w.s[b];
        _Float16* dst = w.d[b];
        #pragma unroll
        for (int c = 0; c < 8; c++){
            int e8 = c*256 + t;                 // 2048 chunks of 8 elems
            int k = e8 >> 4, n0 = (e8 & 15) * 8;
            float4 f0 = *(const float4*)(src + k*128 + n0);
            float4 f1 = *(const float4*)(src + k*128 + n0 + 4);
            T[(n0+0)*136 + k] = (_Float16)f0.x;
            T[(n0+1)*136 + k] = (_Float16)f0.y;
            T[(n0+2)*136 + k] = (_Float16)f0.z;
            T[(n0+3)*136 + k] = (_Float16)f0.w;
            T[(n0+4)*136 + k] = (_Float16)f1.x;
            T[(n0+5)*136 + k] = (_Float16)f1.y;
            T[(n0+6)*136 + k] = (_Float16)f1.z;
            T[(n0+7)*136 + k] = (_Float16)f1.w;
        }
        __syncthreads();
        #pragma unroll
        for (int c = 0; c < 8; c++){
            int e8 = c*256 + t;
            int n = e8 >> 4, k0 = (e8 & 15) * 8;
            *(uint4*)(dst + n*128 + k0) = *(const uint4*)(&T[n*136 + k0]);
        }
    } else if (b < 266){
        cnt[(b - 10)*256 + t] = 1u;             // self-loop pre-counted
    } else {
        // c1'[l][j] = gb1[j] + sum_k lb2[k]*gw1[k][j]   (folds b2 out of k_edge)
        int l = b - 266;
        int j = t;
        if (j < 128){
            const float* lb2 = l ? lb2_1 : lb2_0;
            const float* gw1 = l ? gw1_1 : gw1_0;
            float s = (l ? gb1_1 : gb1_0)[j];
            for (int k = 0; k < 128; k++) s += lb2[k] * gw1[k*128 + j];
            c1p[l*128 + j] = s;
        }
    }
}

// ---------------- pure histogram (un-fused from ab3 so scan1 starts sooner) ----
__global__ void k_hist(const int* __restrict__ ei, uint32_t* cnt){
    int e = blockIdx.x * 512 + threadIdx.x;      // grid = NE/512 exactly
    atomicAdd(&cnt[ei[NE + e]], 1u);
}

__global__ void k_scan1(const uint32_t* __restrict__ cnt, uint32_t* __restrict__ bsum){
    __shared__ uint32_t ps[256];
    int t = threadIdx.x;
    ps[t] = cnt[blockIdx.x*256 + t]; __syncthreads();
    for (int off = 128; off > 0; off >>= 1){
        if (t < off) ps[t] += ps[t + off];
        __syncthreads();
    }
    if (t == 0) bsum[blockIdx.x] = ps[0];
}
// fused scan2+scan3: each block re-derives its bsum-prefix offset in LDS
__global__ void k_scan23(const uint32_t* __restrict__ cnt, const uint32_t* __restrict__ bsum,
                         uint32_t* __restrict__ cur){
    __shared__ uint32_t ps[256];
    __shared__ uint32_t bs[256];
    int t = threadIdx.x, b = blockIdx.x, i = b*256 + t;
    uint32_t bb = bsum[b];
    bs[t] = bsum[t];
    uint32_t v = cnt[i];
    ps[t] = v; __syncthreads();
    for (int off = 1; off < 256; off <<= 1){
        uint32_t u = (t >= off) ? ps[t - off] : 0u;
        uint32_t w = (t >= off) ? bs[t - off] : 0u;
        __syncthreads();
        ps[t] += u; bs[t] += w;
        __syncthreads();
    }
    cur[i] = (bs[b] - bb) + ps[t] - v;
}

// ---------------- fused scatter + ab3 (mutually independent; both gate edge0) ----
// blocks 0..511: ab3 (512 thr, 128-row tiles, single-acc ordering);
// blocks 512..2687: edge scatter (512 edges/block, E2/512 = 2176 blocks).
__launch_bounds__(512, 4)
__global__ void k_scatab3(const int* __restrict__ ei, uint32_t* __restrict__ cur,
                          uint2* __restrict__ sedge,
                          const float* __restrict__ x, const float* __restrict__ pos,
                          const _Float16* __restrict__ w1aT0, const _Float16* __restrict__ w1bT0,
                          const _Float16* __restrict__ w1bT1, const float* __restrict__ lb1_0,
                          _Float16* __restrict__ Ah, _Float16* __restrict__ Bh0,
                          _Float16* __restrict__ Bh1, uint32_t* __restrict__ agg){
    __shared__ _Float16 Ts[128*LP];
    __shared__ _Float16 Ws[128*128];
    __shared__ float b1s[128];
    const int tid = threadIdx.x;

    if (blockIdx.x >= 512){                            // ---- scatter part ----
        int e = (blockIdx.x - 512) * 512 + tid;
        uint32_t s, d;
        if (e < NE){ s = (uint32_t)ei[e]; d = (uint32_t)ei[NE + e]; }
        else { s = d = (uint32_t)(e - NE); }
        uint32_t p = atomicAdd(&cur[d], 1u);
        sedge[p] = make_uint2(s, d);
        return;
    }

    const int node0 = blockIdx.x * 128;
    const int wv = tid >> 6, lane = tid & 63, lq = lane & 15, quad = lane >> 4;
    if (tid < 128) b1s[tid] = lb1_0[tid];

    {   // init agg for this node range (128 rows = 16384 words)
        uint4* ap = (uint4*)(agg + (size_t)node0 * HID);
        uint4 v = make_uint4(ENC_NEG, ENC_NEG, ENC_NEG, ENC_NEG);
        #pragma unroll
        for (int i = 0; i < 8; i++) ap[tid + i*512] = v;
    }
    // stage pos -> Ts (chunk-linear coalesced; 2048 16B-chunks / 512 thr = 4 each)
    #pragma unroll
    for (int i = 0; i < 4; i++){
        int chunk = tid + i*512;
        int row = chunk >> 4, qc = chunk & 15;
        const float4* src = (const float4*)(pos + (size_t)(node0 + row)*HID + qc*8);
        float4 f0 = src[0], f1 = src[1];
        uint4 o; o.x = pkh(f0.x, f0.y); o.y = pkh(f0.z, f0.w);
        o.z = pkh(f1.x, f1.y); o.w = pkh(f1.z, f1.w);
        *(uint4*)(Ts + row*LP + qc*8) = o;
    }
    dma_w8(w1bT1, Ws, wv, lane);
    __syncthreads();                                   // bar1: Ts+Ws ready

    f32x4 acc[8];
    zero_acc8(acc);
    gemm_w(Ts, Ws, acc, wv, lq, quad);                 // pos @ W1b1
    __syncthreads();                                   // bar2: Ws readers done
    dma_w8(w1bT0, Ws, wv, lane);
    #pragma unroll
    for (int ct = 0; ct < 8; ct++)
        #pragma unroll
        for (int rg = 0; rg < 4; rg++)
            Bh1[(size_t)(node0 + wv*16 + quad*4 + rg)*HID + ct*16 + lq]
                = (_Float16)acc[ct][rg];
    __syncthreads();                                   // bar3: Ws=W1b0 ready

    zero_acc8(acc);
    gemm_w(Ts, Ws, acc, wv, lq, quad);                 // acc = pos @ W1b0 (kept)
    __syncthreads();                                   // bar4: Ts+Ws readers done

    #pragma unroll
    for (int i = 0; i < 4; i++){                       // stage x -> Ts
        int chunk = tid + i*512;
        int row = chunk >> 4, qc = chunk & 15;
        const float4* src = (const float4*)(x + (size_t)(node0 + row)*HID + qc*8);
        float4 f0 = src[0], f1 = src[1];
        uint4 o; o.x = pkh(f0.x, f0.y); o.y = pkh(f0.z, f0.w);
        o.z = pkh(f1.x, f1.y); o.w = pkh(f1.z, f1.w);
        *(uint4*)(Ts + row*LP + qc*8) = o;
    }
    dma_w8(w1aT0, Ws, wv, lane);
    #pragma unroll
    for (int ct = 0; ct < 8; ct++)                     // store B0 (acc kept live)
        #pragma unroll
        for (int rg = 0; rg < 4; rg++)
            Bh0[(size_t)(node0 + wv*16 + quad*4 + rg)*HID + ct*16 + lq]
                = (_Float16)acc[ct][rg];
    __syncthreads();                                   // bar5: Ts=x + Ws=W1a0 ready

    gemm_w(Ts, Ws, acc, wv, lq, quad);                 // acc += x @ W1a0

    #pragma unroll
    for (int ct = 0; ct < 8; ct++)
        #pragma unroll
        for (int rg = 0; rg < 4; rg++){
            int c = ct*16 + lq;
            Ah[(size_t)(node0 + wv*16 + quad*4 + rg)*HID + c]
                = (_Float16)(acc[ct][rg] + b1s[c]);
        }
}

// -------- edge kernel: agg[dst] = max over edges of relu(A[src]-B[dst]) @ W2 --------
// R4 structure (proven). `base`: global block offset so a dispatch can cover a
// half-range (layer-0 split into two for top-5 visibility; swizzle stays bijective).
__launch_bounds__(256, 4)
__global__ void k_edge(const uint2* __restrict__ sedge,
                       const _Float16* __restrict__ Ah, const _Float16* __restrict__ Bh,
                       const _Float16* __restrict__ w2T,
                       uint32_t* __restrict__ agg, int base){
    __shared__ _Float16 Ws[128*128];                 // 32768 B, swizzled W2
    __shared__ __align__(16) uint32_t tab[TABW];     // 6720 B run-table (own region)
    __shared__ int ds_s[128];
    __shared__ unsigned long long masks_s[2];
    __shared__ int run_dst_s[RMAX];
    const int tid = threadIdx.x;
    const int bid = blockIdx.x + base;
    const int lb  = (bid & 7) * (E2/128/8) + (bid >> 3);   // XCD swizzle
    const int e0 = lb * 128;
    const int wv = tid >> 6, lane = tid & 63, lq = lane & 15, quad = lane >> 4;
    const int r0 = wv*32 + lq, r1 = r0 + 16;

    // ---- edge loads first (oldest in vmem FIFO -> cheap counted wait) ----
    const uint2 ea = sedge[e0 + r0];
    const uint2 eb = sedge[e0 + r1];
    int d_cur = 0;
    if (tid < 128) d_cur = (int)sedge[e0 + tid].y;

    // ---- W2 global->LDS DMA: linear dest, inverse-swizzled source ----
    dma_w(w2T, Ws, wv, lane);

    // gathers: issue ASAP; drain at barrier1 under DMA + LDS bookkeeping
    const _Float16* a0p = Ah + (size_t)ea.x*HID + quad*8;
    const _Float16* a1p = Ah + (size_t)eb.x*HID + quad*8;
    const _Float16* b0p = Bh + (size_t)ea.y*HID + quad*8;
    const _Float16* b1p = Bh + (size_t)eb.y*HID + quad*8;
    h8v A0[4], A1[4], B0[4], B1[4];
    #pragma unroll
    for (int i = 0; i < 4; i++){
        A0[i] = *(const h8v*)(a0p + 32*i);
        A1[i] = *(const h8v*)(a1p + 32*i);
        B0[i] = *(const h8v*)(b0p + 32*i);
        B1[i] = *(const h8v*)(b1p + 32*i);
    }

    // boundary flags: d_prev via in-wave shuffles (no extra global loads).
    // lanes with (r1==63) hold sedge[e0+63] in eb -> shfl lane 15 serves tid 64.
    bool flag = false;
    if (tid < 128){
        ds_s[tid] = d_cur;
        int d_up  = __shfl_up(d_cur, 1);
        int d_b63 = __shfl((int)eb.y, 15);
        if (tid & 63) flag = (d_cur != d_up);
        else          flag = (tid == 0) ? true : (d_cur != d_b63);
        unsigned long long m = __ballot(flag);
        if ((tid & 63) == 0) masks_s[tid >> 6] = m;
    }
    {   // init run-table (TABW/4 = 420 uint4)
        uint4* t4 = (uint4*)tab;
        const uint4 vneg = make_uint4(ENC_NEG, ENC_NEG, ENC_NEG, ENC_NEG);
        #pragma unroll
        for (int i = 0; i < 2; i++){
            int idx = tid + i*256;
            if (idx < TABW/4) t4[idx] = vneg;
        }
    }
    __syncthreads();                            // barrier1: Ws/ds_s/masks/tab ready

    const unsigned long long m0 = masks_s[0], m1 = masks_s[1];
    const int c0 = __popcll(m0);
    const int nruns = c0 + __popcll(m1);

    // boundary threads record their run's dst (read post-barrier2 only)
    if (flag){
        int r;
        if (tid < 64) r = __popcll(m0 & ((2ull << tid) - 1)) - 1;
        else          r = c0 + __popcll(m1 & ((2ull << (tid-64)) - 1)) - 1;
        if (r < RMAX) run_dst_s[r] = d_cur;
    }

    f32x4 acc[2][8];
    zero_acc(acc);

    const h8v zero8 = (h8v)(_Float16)0;
    #pragma unroll
    for (int i = 0; i < 4; i++){
        h8v a0 = __builtin_elementwise_max(A0[i] - B0[i], zero8);
        h8v a1 = __builtin_elementwise_max(A1[i] - B1[i], zero8);
        const int kcb = i*4;
        #pragma unroll
        for (int ct = 0; ct < 8; ct++){
            h8v b = *(const h8v*)(Ws + (ct*16 + lq)*128 + (((kcb + quad) ^ lq) << 3));
            acc[0][ct] = __builtin_amdgcn_mfma_f32_16x16x32_f16(a0, b, acc[0][ct], 0, 0, 0);
            acc[1][ct] = __builtin_amdgcn_mfma_f32_16x16x32_f16(a1, b, acc[1][ct], 0, 0, 0);
        }
    }

    // flush acc -> run-table (tab does not alias Ws: no barrier needed)
    #pragma unroll
    for (int rt = 0; rt < 2; rt++){
        const int rb = wv*32 + rt*16 + quad*4;
        int rid[4];
        #pragma unroll
        for (int i = 0; i < 4; i++){
            int r = rb + i;
            if (r < 64) rid[i] = __popcll(m0 & ((2ull << r) - 1)) - 1;
            else        rid[i] = c0 + __popcll(m1 & ((2ull << (r-64)) - 1)) - 1;
        }
        const bool b01 = rid[1] != rid[0];
        const bool b12 = rid[2] != rid[1];
        const bool b23 = rid[3] != rid[2];
        #pragma unroll
        for (int ct = 0; ct < 8; ct++){
            const int c = ct*16 + lq;
            float v0 = acc[rt][ct][0], v1 = acc[rt][ct][1];
            float v2 = acc[rt][ct][2], v3 = acc[rt][ct][3];
            #define FLUSH(ID, R, V) do{ uint32_t ev = encf(V); \
                if (__builtin_expect((ID) < RMAX, 1)) atomicMax(&tab[(ID)*TP + c], ev); \
                else atomicMax(&agg[(size_t)ds_s[R]*HID + c], ev); }while(0)
            if (b01) FLUSH(rid[0], rb+0, v0); else v1 = fmaxf(v1, v0);
            if (b12) FLUSH(rid[1], rb+1, v1); else v2 = fmaxf(v2, v1);
            if (b23) FLUSH(rid[2], rb+2, v2); else v3 = fmaxf(v3, v2);
            FLUSH(rid[3], rb+3, v3);
            #undef FLUSH
        }
    }
    __syncthreads();                            // barrier2: table + run_dst complete

    {   // flush: boundary runs -> atomicMax; interior runs sole-writer -> plain store
        const int c = tid & 127;
        const int ntab = nruns < RMAX ? nruns : RMAX;
        for (int r = tid >> 7; r < ntab; r += 2){
            uint32_t v = tab[r*TP + c];
            uint32_t* dst = &agg[(size_t)run_dst_s[r]*HID + c];
            if (r == 0 || r == nruns-1 || nruns > RMAX) atomicMax(dst, v);
            else *dst = v;
        }
    }
}

// -------- fused layer-0 global nn + layer-1 A (512 thr, 128-row tiles) --------
// out0 = relu(agg@G1 + c1')@G2 + c2 ; A1 = out0@W1a1 + B1 + b1_1 ; agg re-init.
__launch_bounds__(512, 4)
__global__ void k_gnn_ab(uint32_t* __restrict__ agg,
                         const _Float16* __restrict__ g1T, const _Float16* __restrict__ g2T,
                         const float* __restrict__ c1p, const float* __restrict__ gb2,
                         const _Float16* __restrict__ w1aT1, const _Float16* __restrict__ Bh1,
                         const float* __restrict__ lb1_1,
                         _Float16* __restrict__ Ah){
    __shared__ _Float16 Ts[128*LP];
    __shared__ _Float16 Ws[128*128];
    __shared__ float c1s[128];
    __shared__ float c2s[128];
    __shared__ float b1s[128];
    const int tid = threadIdx.x;
    const int node0 = blockIdx.x * 128;
    const int wv = tid >> 6, lane = tid & 63, lq = lane & 15, quad = lane >> 4;
    if (tid < 128){ c1s[tid] = c1p[tid]; c2s[tid] = gb2[tid]; b1s[tid] = lb1_1[tid]; }

    {   // decode agg -> Ts (+re-init), chunk-linear coalesced (4096 uint4 / 512)
        const uint4 vneg = make_uint4(ENC_NEG, ENC_NEG, ENC_NEG, ENC_NEG);
        #pragma unroll
        for (int i = 0; i < 8; i++){
            int chunk = tid + i*512;
            int row = chunk >> 5, qc = chunk & 31;
            uint4* ga = (uint4*)(agg + (size_t)(node0 + row)*HID + qc*4);
            uint4 u = *ga; *ga = vneg;
            uint2 o; o.x = pkh(decf(u.x), decf(u.y)); o.y = pkh(decf(u.z), decf(u.w));
            *(uint2*)(Ts + row*LP + qc*4) = o;
        }
    }
    dma_w8(g1T, Ws, wv, lane);
    __syncthreads();                                   // bar1

    f32x4 acc[8];
    zero_acc8(acc);
    gemm_w(Ts, Ws, acc, wv, lq, quad);                 // agg @ G1
    __syncthreads();                                   // bar2: Ts+Ws readers done
    dma_w8(g2T, Ws, wv, lane);
    #pragma unroll
    for (int ct = 0; ct < 8; ct++)
        #pragma unroll
        for (int rg = 0; rg < 4; rg++){
            int c = ct*16 + lq;
            Ts[(wv*16 + quad*4 + rg)*LP + c] = (_Float16)fmaxf(acc[ct][rg] + c1s[c], 0.f);
        }
    __syncthreads();                                   // bar3

    zero_acc8(acc);
    gemm_w(Ts, Ws, acc, wv, lq, quad);                 // P @ G2
    __syncthreads();                                   // bar4
    dma_w8(w1aT1, Ws, wv, lane);
    #pragma unroll
    for (int ct = 0; ct < 8; ct++)
        #pragma unroll
        for (int rg = 0; rg < 4; rg++){
            int c = ct*16 + lq;
            Ts[(wv*16 + quad*4 + rg)*LP + c] = (_Float16)(acc[ct][rg] + c2s[c]);
        }
    __syncthreads();                                   // bar5

    // prefetch Bh1 residual into regs (latency hidden under GEMM3)
    _Float16 bres[8][4];
    #pragma unroll
    for (int ct = 0; ct < 8; ct++)
        #pragma unroll
        for (int rg = 0; rg < 4; rg++)
            bres[ct][rg] = Bh1[(size_t)(node0 + wv*16 + quad*4 + rg)*HID + ct*16 + lq];

    zero_acc8(acc);
    gemm_w(Ts, Ws, acc, wv, lq, quad);                 // out0 @ W1a1

    #pragma unroll
    for (int ct = 0; ct < 8; ct++)
        #pragma unroll
        for (int rg = 0; rg < 4; rg++){
            int c = ct*16 + lq;
            float v = acc[ct][rg] + (float)bres[ct][rg] + b1s[c];
            Ah[(size_t)(node0 + wv*16 + quad*4 + rg)*HID + c] = (_Float16)v;
        }
}

// -------- final global nn (512 thr, 128-row tiles): relu(agg@G1+c1')@G2 + c2 ----
__launch_bounds__(512, 4)
__global__ void k_gnn(const uint32_t* __restrict__ agg,
                      const _Float16* __restrict__ g1T, const _Float16* __restrict__ g2T,
                      const float* __restrict__ c1p, const float* __restrict__ gb2,
                      float* __restrict__ outf){
    __shared__ _Float16 Ts[128*LP];
    __shared__ _Float16 Ws[128*128];
    __shared__ float c1s[128];
    __shared__ float c2s[128];
    const int tid = threadIdx.x;
    const int node0 = blockIdx.x * 128;
    const int wv = tid >> 6, lane = tid & 63, lq = lane & 15, quad = lane >> 4;
    if (tid < 128){ c1s[tid] = c1p[tid]; c2s[tid] = gb2[tid]; }

    {   // decode agg -> Ts, chunk-linear coalesced
        #pragma unroll
        for (int i = 0; i < 8; i++){
            int chunk = tid + i*512;
            int row = chunk >> 5, qc = chunk & 31;
            const uint4* ga = (const uint4*)(agg + (size_t)(node0 + row)*HID + qc*4);
            uint4 u = *ga;
            uint2 o; o.x = pkh(decf(u.x), decf(u.y)); o.y = pkh(decf(u.z), decf(u.w));
            *(uint2*)(Ts + row*LP + qc*4) = o;
        }
    }
    dma_w8(g1T, Ws, wv, lane);
    __syncthreads();                                   // bar1

    f32x4 acc[8];
    zero_acc8(acc);
    gemm_w(Ts, Ws, acc, wv, lq, quad);                 // agg @ G1
    __syncthreads();                                   // bar2
    dma_w8(g2T, Ws, wv, lane);
    #pragma unroll
    for (int ct = 0; ct < 8; ct++)
        #pragma unroll
        for (int rg = 0; rg < 4; rg++){
            int c = ct*16 + lq;
            Ts[(wv*16 + quad*4 + rg)*LP + c] = (_Float16)fmaxf(acc[ct][rg] + c1s[c], 0.f);
        }
    __syncthreads();                                   // bar3

    zero_acc8(acc);
    gemm_w(Ts, Ws, acc, wv, lq, quad);                 // P @ G2

    #pragma unroll
    for (int ct = 0; ct < 8; ct++)
        #pragma unroll
        for (int rg = 0; rg < 4; rg++){
            int c = ct*16 + lq;
            outf[(size_t)(node0 + wv*16 + quad*4 + rg)*HID + c] = acc[ct][rg] + c2s[c];
        }
}

extern "C" void kernel_launch(void* const* d_in, const int* in_sizes, int n_in,
                              void* d_out, int out_size, void* d_ws, size_t ws_size,
                              hipStream_t stream){
    const float* x   = (const float*)d_in[0];
    const float* pos = (const float*)d_in[1];
    const int*   ei  = (const int*)d_in[2];
    const float* W[16];
    for (int i = 0; i < 16; i++) W[i] = (const float*)d_in[3 + i];
    // per layer l: lw1=W[8l+0] lb1=+1 lw2=+2 lb2=+3 gw1=+4 gb1=+5 gw2=+6 gb2=+7

    uint8_t* p = (uint8_t*)d_ws;
    _Float16* wT[10];
    for (int i = 0; i < 10; i++) wT[i] = (_Float16*)(p + (size_t)i * 32768);
    size_t off = 10 * 32768;
    _Float16* Ah  = (_Float16*)(p + off); off += (size_t)NN * HID * 2;
    _Float16* Bh0 = (_Float16*)(p + off); off += (size_t)NN * HID * 2;
    _Float16* Bh1 = (_Float16*)(p + off); off += (size_t)NN * HID * 2;
    uint32_t* agg = (uint32_t*)(p + off); off += (size_t)NN * HID * 4;
    uint32_t* cnt = (uint32_t*)(p + off); off += (size_t)NN * 4;
    uint32_t* cur = (uint32_t*)(p + off); off += (size_t)NN * 4;
    uint32_t* bsum = (uint32_t*)(p + off); off += 256 * 4;
    uint32_t* bofs = (uint32_t*)(p + off); off += 256 * 4;
    float* c1p = (float*)(p + off); off += 256 * 4;
    uint2* sedge = (uint2*)(p + off); off += (size_t)E2 * 8;
    (void)ws_size; (void)in_sizes; (void)n_in; (void)out_size; (void)bofs;

    // weight transpose slots per layer: W1a^T, W1b^T, W2^T, G1^T, G2^T
    WT wt;
    for (int l = 0; l < 2; l++){
        wt.s[5*l + 0] = W[8*l + 0];
        wt.s[5*l + 1] = W[8*l + 0] + 128*128;
        wt.s[5*l + 2] = W[8*l + 2];
        wt.s[5*l + 3] = W[8*l + 4];
        wt.s[5*l + 4] = W[8*l + 6];
        for (int j = 0; j < 5; j++) wt.d[5*l + j] = wT[5*l + j];
    }
    k_prep<<<268, 256, 0, stream>>>(wt, cnt, W[3], W[4], W[5], W[11], W[12], W[13], c1p);

    // sort chain head: pure hist (no longer delayed by ab3's GEMMs)
    k_hist<<<NE/512, 512, 0, stream>>>(ei, cnt);
    k_scan1<<<256, 256, 0, stream>>>(cnt, bsum);
    k_scan23<<<256, 256, 0, stream>>>(cnt, bsum, cur);
    // scatter (blocks 512..2687) fused with ab3 (blocks 0..511) -- independent work
    k_scatab3<<<512 + E2/512, 512, 0, stream>>>(ei, cur, sedge, x, pos,
                                                wT[0], wT[1], wT[6], W[1],
                                                Ah, Bh0, Bh1, agg);

    // layer-0 edges split in two for rocprof top-5 visibility of non-edge kernels
    k_edge<<<E2/256, 256, 0, stream>>>(sedge, Ah, Bh0, wT[2], agg, 0);
    k_edge<<<E2/256, 256, 0, stream>>>(sedge, Ah, Bh0, wT[2], agg, E2/256);
    k_gnn_ab<<<NN/128, 512, 0, stream>>>(agg, wT[3], wT[4], c1p, W[7],
                                         wT[5], Bh1, W[9], Ah);
    k_edge<<<E2/128, 256, 0, stream>>>(sedge, Ah, Bh1, wT[7], agg, 0);
    k_gnn<<<NN/128, 512, 0, stream>>>(agg, wT[8], wT[9], c1p + 128, W[15],
                                      (float*)d_out);
}

// Round 11
// 411.172 us; speedup vs baseline: 1.1121x; 1.1121x over previous
//
#include <hip/hip_runtime.h>
#include <hip/hip_bf16.h>
#include <stdint.h>

#define NN 65536
#define NE 1048576
#define E2 (NE + NN)      // edges + self loops = 1,114,112 = 8704*128
#define HID 128
#define LP 136            // padded LDS row pitch (fp16 elems) for node-kernel A tiles
#define RMAX 13           // max runs in LDS run-table (overflow -> global atomics)
#define TP 129            // run-table stride in words
#define TABW 1680         // ceil(RMAX*TP/4)*4 words
#define ENC_NEG 0x007FFFFFu   // encf(-inf)

typedef _Float16 h8v __attribute__((ext_vector_type(8)));
typedef __fp16 fp16x2 __attribute__((ext_vector_type(2)));
typedef __attribute__((ext_vector_type(4))) float f32x4;

__device__ __forceinline__ uint32_t pkh(float a, float b){
    union { fp16x2 h; uint32_t u; } v;
    v.h = __builtin_amdgcn_cvt_pkrtz(a, b);
    return v.u;
}
// monotone float->uint encoding for unsigned atomicMax (branchless)
__device__ __forceinline__ uint32_t encf(float x){
    union { float f; uint32_t u; } v; v.f = x;
    return v.u ^ (uint32_t)(((int32_t)v.u >> 31) | 0x80000000);
}
__device__ __forceinline__ float decf(uint32_t u){
    union { uint32_t u; float f; } v;
    v.u = u ^ (uint32_t)(~((int32_t)u >> 31) | 0x80000000);
    return v.f;
}

// direct global->LDS DMA, 16B per lane (dest = wave-uniform base + lane*16)
__device__ __forceinline__ void gl_lds16(const _Float16* g, _Float16* l){
    __builtin_amdgcn_global_load_lds(
        (const __attribute__((address_space(1))) uint32_t*)g,
        (__attribute__((address_space(3))) uint32_t*)l, 16, 0, 0);
}

// stage a 128x128 fp16 weight into LDS via DMA (4-wave version, k_edge):
// linear dest, inverse-XOR-swizzled per-lane global source.
__device__ __forceinline__ void dma_w(const _Float16* __restrict__ wT, _Float16* Ws,
                                      int wv, int lane){
    #pragma unroll
    for (int rnd = 0; rnd < 8; rnd++){
        int g = rnd*256 + wv*64 + lane;              // 16B chunk id 0..2047
        int r = g >> 4, kc = g & 15;
        gl_lds16(wT + r*HID + ((kc ^ (r & 15)) << 3),
                 Ws + rnd*2048 + wv*512);
    }
}
// 8-wave version (512-thread node kernels): same layout, 4 rounds.
__device__ __forceinline__ void dma_w8(const _Float16* __restrict__ wT, _Float16* Ws,
                                       int wv, int lane){
    #pragma unroll
    for (int rnd = 0; rnd < 4; rnd++){
        int g = rnd*512 + wv*64 + lane;              // 16B chunk id 0..2047
        int r = g >> 4, kc = g & 15;
        gl_lds16(wT + r*HID + ((kc ^ (r & 15)) << 3),
                 Ws + rnd*4096 + wv*512);
    }
}

// per-wave 16x128x128 fp16 GEMM slice: A rows wv*16..+15 from padded LDS tile,
// B from swizzled Ws. acc[ct] covers col ct*16+lq, rows quad*4+rg.
// R5 lesson: weights must be LDS-resident, not direct-global.
__device__ __forceinline__ void gemm_w(const _Float16* Ts, const _Float16* Ws,
                                       f32x4 (&acc)[8], int wv, int lq, int quad){
    #pragma unroll
    for (int k0 = 0; k0 < 128; k0 += 32){
        h8v af = *(const h8v*)(Ts + (wv*16 + lq)*LP + k0 + quad*8);
        const int kcb = k0 >> 3;
        #pragma unroll
        for (int ct = 0; ct < 8; ct++){
            h8v b = *(const h8v*)(Ws + (ct*16 + lq)*128 + (((kcb + quad) ^ lq) << 3));
            acc[ct] = __builtin_amdgcn_mfma_f32_16x16x32_f16(af, b, acc[ct], 0, 0, 0);
        }
    }
}

__device__ __forceinline__ void zero_acc8(f32x4 (&acc)[8]){
    #pragma unroll
    for (int b = 0; b < 8; b++) acc[b] = (f32x4){0.f, 0.f, 0.f, 0.f};
}

__device__ __forceinline__ void zero_acc(f32x4 (&acc)[2][8]){
    #pragma unroll
    for (int a = 0; a < 2; a++)
        #pragma unroll
        for (int b = 0; b < 8; b++)
            acc[a][b] = (f32x4){0.f, 0.f, 0.f, 0.f};
}

// ---------------- prep: weight transposes + cnt init + folded bias ----------------
// Coalesced transpose (R9): float4 row reads -> LDS transpose -> uint4 writes.
struct WT { const float* s[10]; _Float16* d[10]; };
__global__ void k_prep(WT w, uint32_t* cnt,
                       const float* lb2_0, const float* gw1_0, const float* gb1_0,
                       const float* lb2_1, const float* gw1_1, const float* gb1_1,
                       float* c1p){
    int b = blockIdx.x;
    int t = threadIdx.x;
    if (b < 10){
        __shared__ _Float16 T[128*136];
        const float* src = w.s[b];
        _Float16* dst = w.d[b];
        #pragma unroll
        for (int c = 0; c < 8; c++){
            int e8 = c*256 + t;                 // 2048 chunks of 8 elems
            int k = e8 >> 4, n0 = (e8 & 15) * 8;
            float4 f0 = *(const float4*)(src + k*128 + n0);
            float4 f1 = *(const float4*)(src + k*128 + n0 + 4);
            T[(n0+0)*136 + k] = (_Float16)f0.x;
            T[(n0+1)*136 + k] = (_Float16)f0.y;
            T[(n0+2)*136 + k] = (_Float16)f0.z;
            T[(n0+3)*136 + k] = (_Float16)f0.w;
            T[(n0+4)*136 + k] = (_Float16)f1.x;
            T[(n0+5)*136 + k] = (_Float16)f1.y;
            T[(n0+6)*136 + k] = (_Float16)f1.z;
            T[(n0+7)*136 + k] = (_Float16)f1.w;
        }
        __syncthreads();
        #pragma unroll
        for (int c = 0; c < 8; c++){
            int e8 = c*256 + t;
            int n = e8 >> 4, k0 = (e8 & 15) * 8;
            *(uint4*)(dst + n*128 + k0) = *(const uint4*)(&T[n*136 + k0]);
        }
    } else if (b < 266){
        cnt[(b - 10)*256 + t] = 1u;             // self-loop pre-counted
    } else {
        // c1'[l][j] = gb1[j] + sum_k lb2[k]*gw1[k][j]   (folds b2 out of k_edge)
        int l = b - 266;
        int j = t;
        if (j < 128){
            const float* lb2 = l ? lb2_1 : lb2_0;
            const float* gw1 = l ? gw1_1 : gw1_0;
            float s = (l ? gb1_1 : gb1_0)[j];
            for (int k = 0; k < 128; k++) s += lb2[k] * gw1[k*128 + j];
            c1p[l*128 + j] = s;
        }
    }
}

// ---------------- fused hist + ab3 (512 threads, 128-row tiles) ----------------
// blocks 0..511: ab3 (single-acc ordering); blocks 512..2559: edge histogram.
// R11: hist also records rank[e] = old count -> scatter becomes atomic-free.
__launch_bounds__(512, 4)
__global__ void k_histab3(const int* __restrict__ ei, uint32_t* __restrict__ cnt,
                          uint32_t* __restrict__ rank,
                          const float* __restrict__ x, const float* __restrict__ pos,
                          const _Float16* __restrict__ w1aT0, const _Float16* __restrict__ w1bT0,
                          const _Float16* __restrict__ w1bT1, const float* __restrict__ lb1_0,
                          _Float16* __restrict__ Ah, _Float16* __restrict__ Bh0,
                          _Float16* __restrict__ Bh1, uint32_t* __restrict__ agg){
    __shared__ _Float16 Ts[128*LP];
    __shared__ _Float16 Ws[128*128];
    __shared__ float b1s[128];
    const int tid = threadIdx.x;

    if (blockIdx.x >= 512){                            // ---- histogram part ----
        int e = (blockIdx.x - 512) * 512 + tid;
        rank[e] = atomicAdd(&cnt[ei[NE + e]], 1u);     // rank 1..deg (1 = self-loop slot 0)
        return;
    }

    const int node0 = blockIdx.x * 128;
    const int wv = tid >> 6, lane = tid & 63, lq = lane & 15, quad = lane >> 4;
    if (tid < 128) b1s[tid] = lb1_0[tid];

    {   // init agg for this node range (128 rows = 16384 words)
        uint4* ap = (uint4*)(agg + (size_t)node0 * HID);
        uint4 v = make_uint4(ENC_NEG, ENC_NEG, ENC_NEG, ENC_NEG);
        #pragma unroll
        for (int i = 0; i < 8; i++) ap[tid + i*512] = v;
    }
    // stage pos -> Ts (chunk-linear coalesced; 2048 16B-chunks / 512 thr = 4 each)
    #pragma unroll
    for (int i = 0; i < 4; i++){
        int chunk = tid + i*512;
        int row = chunk >> 4, qc = chunk & 15;
        const float4* src = (const float4*)(pos + (size_t)(node0 + row)*HID + qc*8);
        float4 f0 = src[0], f1 = src[1];
        uint4 o; o.x = pkh(f0.x, f0.y); o.y = pkh(f0.z, f0.w);
        o.z = pkh(f1.x, f1.y); o.w = pkh(f1.z, f1.w);
        *(uint4*)(Ts + row*LP + qc*8) = o;
    }
    dma_w8(w1bT1, Ws, wv, lane);
    __syncthreads();                                   // bar1: Ts+Ws ready

    f32x4 acc[8];
    zero_acc8(acc);
    gemm_w(Ts, Ws, acc, wv, lq, quad);                 // pos @ W1b1
    __syncthreads();                                   // bar2: Ws readers done
    dma_w8(w1bT0, Ws, wv, lane);
    #pragma unroll
    for (int ct = 0; ct < 8; ct++)
        #pragma unroll
        for (int rg = 0; rg < 4; rg++)
            Bh1[(size_t)(node0 + wv*16 + quad*4 + rg)*HID + ct*16 + lq]
                = (_Float16)acc[ct][rg];
    __syncthreads();                                   // bar3: Ws=W1b0 ready

    zero_acc8(acc);
    gemm_w(Ts, Ws, acc, wv, lq, quad);                 // acc = pos @ W1b0 (kept)
    __syncthreads();                                   // bar4: Ts+Ws readers done

    #pragma unroll
    for (int i = 0; i < 4; i++){                       // stage x -> Ts
        int chunk = tid + i*512;
        int row = chunk >> 4, qc = chunk & 15;
        const float4* src = (const float4*)(x + (size_t)(node0 + row)*HID + qc*8);
        float4 f0 = src[0], f1 = src[1];
        uint4 o; o.x = pkh(f0.x, f0.y); o.y = pkh(f0.z, f0.w);
        o.z = pkh(f1.x, f1.y); o.w = pkh(f1.z, f1.w);
        *(uint4*)(Ts + row*LP + qc*8) = o;
    }
    dma_w8(w1aT0, Ws, wv, lane);
    #pragma unroll
    for (int ct = 0; ct < 8; ct++)                     // store B0 (acc kept live)
        #pragma unroll
        for (int rg = 0; rg < 4; rg++)
            Bh0[(size_t)(node0 + wv*16 + quad*4 + rg)*HID + ct*16 + lq]
                = (_Float16)acc[ct][rg];
    __syncthreads();                                   // bar5: Ts=x + Ws=W1a0 ready

    gemm_w(Ts, Ws, acc, wv, lq, quad);                 // acc += x @ W1a0

    #pragma unroll
    for (int ct = 0; ct < 8; ct++)
        #pragma unroll
        for (int rg = 0; rg < 4; rg++){
            int c = ct*16 + lq;
            Ah[(size_t)(node0 + wv*16 + quad*4 + rg)*HID + c]
                = (_Float16)(acc[ct][rg] + b1s[c]);
        }
}

__global__ void k_scan1(const uint32_t* __restrict__ cnt, uint32_t* __restrict__ bsum){
    __shared__ uint32_t ps[256];
    int t = threadIdx.x;
    ps[t] = cnt[blockIdx.x*256 + t]; __syncthreads();
    for (int off = 128; off > 0; off >>= 1){
        if (t < off) ps[t] += ps[t + off];
        __syncthreads();
    }
    if (t == 0) bsum[blockIdx.x] = ps[0];
}
// fused scan2+scan3: each block re-derives its bsum-prefix offset in LDS
__global__ void k_scan23(const uint32_t* __restrict__ cnt, const uint32_t* __restrict__ bsum,
                         uint32_t* __restrict__ cur){
    __shared__ uint32_t ps[256];
    __shared__ uint32_t bs[256];
    int t = threadIdx.x, b = blockIdx.x, i = b*256 + t;
    uint32_t bb = bsum[b];
    bs[t] = bsum[t];
    uint32_t v = cnt[i];
    ps[t] = v; __syncthreads();
    for (int off = 1; off < 256; off <<= 1){
        uint32_t u = (t >= off) ? ps[t - off] : 0u;
        uint32_t w = (t >= off) ? bs[t - off] : 0u;
        __syncthreads();
        ps[t] += u; bs[t] += w;
        __syncthreads();
    }
    cur[i] = (bs[b] - bb) + ps[t] - v;
}

// ---------------- atomic-free scatter (R11) ----------------
// p = cur[d] + rank[e] is deterministic (rank captured in hist); sedge packed
// uint32 (s | d<<16, valid since NN = 2^16) -> half the write traffic, and no
// atomic round-trip. Standalone kernel: no LDS -> full occupancy (R10 lesson:
// fusing with ab3 capped scatter at 2 blocks/CU via ab3's 68KB LDS).
__global__ void k_scatter(const int* __restrict__ ei, const uint32_t* __restrict__ cur,
                          const uint32_t* __restrict__ rank,
                          uint32_t* __restrict__ sedge){
    int e = blockIdx.x * 512 + threadIdx.x;
    uint32_t p, v;
    if (e < NE){
        uint32_t s = (uint32_t)ei[e], d = (uint32_t)ei[NE + e];
        p = cur[d] + rank[e];
        v = s | (d << 16);
    } else {
        uint32_t d = (uint32_t)(e - NE);
        p = cur[d];
        v = d | (d << 16);
    }
    sedge[p] = v;
}

// -------- edge kernel: agg[dst] = max over edges of relu(A[src]-B[dst]) @ W2 --------
// R4 structure (proven); R11: sedge packed uint32 (s = lo16, d = hi16).
__launch_bounds__(256, 4)
__global__ void k_edge(const uint32_t* __restrict__ sedge,
                       const _Float16* __restrict__ Ah, const _Float16* __restrict__ Bh,
                       const _Float16* __restrict__ w2T,
                       uint32_t* __restrict__ agg){
    __shared__ _Float16 Ws[128*128];                 // 32768 B, swizzled W2
    __shared__ __align__(16) uint32_t tab[TABW];     // 6720 B run-table (own region)
    __shared__ int ds_s[128];
    __shared__ unsigned long long masks_s[2];
    __shared__ int run_dst_s[RMAX];
    const int tid = threadIdx.x;
    const int bid = blockIdx.x;
    const int lb  = (bid & 7) * (E2/128/8) + (bid >> 3);   // XCD swizzle
    const int e0 = lb * 128;
    const int wv = tid >> 6, lane = tid & 63, lq = lane & 15, quad = lane >> 4;
    const int r0 = wv*32 + lq, r1 = r0 + 16;

    // ---- edge loads first (oldest in vmem FIFO -> cheap counted wait) ----
    const uint32_t ea = sedge[e0 + r0];
    const uint32_t eb = sedge[e0 + r1];
    int d_cur = 0;
    if (tid < 128) d_cur = (int)(sedge[e0 + tid] >> 16);

    // ---- W2 global->LDS DMA: linear dest, inverse-swizzled source ----
    dma_w(w2T, Ws, wv, lane);

    // gathers: issue ASAP; drain at barrier1 under DMA + LDS bookkeeping
    const _Float16* a0p = Ah + (size_t)(ea & 0xFFFFu)*HID + quad*8;
    const _Float16* a1p = Ah + (size_t)(eb & 0xFFFFu)*HID + quad*8;
    const _Float16* b0p = Bh + (size_t)(ea >> 16)*HID + quad*8;
    const _Float16* b1p = Bh + (size_t)(eb >> 16)*HID + quad*8;
    h8v A0[4], A1[4], B0[4], B1[4];
    #pragma unroll
    for (int i = 0; i < 4; i++){
        A0[i] = *(const h8v*)(a0p + 32*i);
        A1[i] = *(const h8v*)(a1p + 32*i);
        B0[i] = *(const h8v*)(b0p + 32*i);
        B1[i] = *(const h8v*)(b1p + 32*i);
    }

    // boundary flags: d_prev via in-wave shuffles (no extra global loads).
    // lanes with (r1==63) hold sedge[e0+63] in eb -> shfl lane 15 serves tid 64.
    bool flag = false;
    if (tid < 128){
        ds_s[tid] = d_cur;
        int d_up  = __shfl_up(d_cur, 1);
        int d_b63 = __shfl((int)(eb >> 16), 15);
        if (tid & 63) flag = (d_cur != d_up);
        else          flag = (tid == 0) ? true : (d_cur != d_b63);
        unsigned long long m = __ballot(flag);
        if ((tid & 63) == 0) masks_s[tid >> 6] = m;
    }
    {   // init run-table (TABW/4 = 420 uint4)
        uint4* t4 = (uint4*)tab;
        const uint4 vneg = make_uint4(ENC_NEG, ENC_NEG, ENC_NEG, ENC_NEG);
        #pragma unroll
        for (int i = 0; i < 2; i++){
            int idx = tid + i*256;
            if (idx < TABW/4) t4[idx] = vneg;
        }
    }
    __syncthreads();                            // barrier1: Ws/ds_s/masks/tab ready

    const unsigned long long m0 = masks_s[0], m1 = masks_s[1];
    const int c0 = __popcll(m0);
    const int nruns = c0 + __popcll(m1);

    // boundary threads record their run's dst (read post-barrier2 only)
    if (flag){
        int r;
        if (tid < 64) r = __popcll(m0 & ((2ull << tid) - 1)) - 1;
        else          r = c0 + __popcll(m1 & ((2ull << (tid-64)) - 1)) - 1;
        if (r < RMAX) run_dst_s[r] = d_cur;
    }

    f32x4 acc[2][8];
    zero_acc(acc);

    const h8v zero8 = (h8v)(_Float16)0;
    #pragma unroll
    for (int i = 0; i < 4; i++){
        h8v a0 = __builtin_elementwise_max(A0[i] - B0[i], zero8);
        h8v a1 = __builtin_elementwise_max(A1[i] - B1[i], zero8);
        const int kcb = i*4;
        #pragma unroll
        for (int ct = 0; ct < 8; ct++){
            h8v b = *(const h8v*)(Ws + (ct*16 + lq)*128 + (((kcb + quad) ^ lq) << 3));
            acc[0][ct] = __builtin_amdgcn_mfma_f32_16x16x32_f16(a0, b, acc[0][ct], 0, 0, 0);
            acc[1][ct] = __builtin_amdgcn_mfma_f32_16x16x32_f16(a1, b, acc[1][ct], 0, 0, 0);
        }
    }

    // flush acc -> run-table (tab does not alias Ws: no barrier needed)
    #pragma unroll
    for (int rt = 0; rt < 2; rt++){
        const int rb = wv*32 + rt*16 + quad*4;
        int rid[4];
        #pragma unroll
        for (int i = 0; i < 4; i++){
            int r = rb + i;
            if (r < 64) rid[i] = __popcll(m0 & ((2ull << r) - 1)) - 1;
            else        rid[i] = c0 + __popcll(m1 & ((2ull << (r-64)) - 1)) - 1;
        }
        const bool b01 = rid[1] != rid[0];
        const bool b12 = rid[2] != rid[1];
        const bool b23 = rid[3] != rid[2];
        #pragma unroll
        for (int ct = 0; ct < 8; ct++){
            const int c = ct*16 + lq;
            float v0 = acc[rt][ct][0], v1 = acc[rt][ct][1];
            float v2 = acc[rt][ct][2], v3 = acc[rt][ct][3];
            #define FLUSH(ID, R, V) do{ uint32_t ev = encf(V); \
                if (__builtin_expect((ID) < RMAX, 1)) atomicMax(&tab[(ID)*TP + c], ev); \
                else atomicMax(&agg[(size_t)ds_s[R]*HID + c], ev); }while(0)
            if (b01) FLUSH(rid[0], rb+0, v0); else v1 = fmaxf(v1, v0);
            if (b12) FLUSH(rid[1], rb+1, v1); else v2 = fmaxf(v2, v1);
            if (b23) FLUSH(rid[2], rb+2, v2); else v3 = fmaxf(v3, v2);
            FLUSH(rid[3], rb+3, v3);
            #undef FLUSH
        }
    }
    __syncthreads();                            // barrier2: table + run_dst complete

    {   // flush: boundary runs -> atomicMax; interior runs sole-writer -> plain store
        const int c = tid & 127;
        const int ntab = nruns < RMAX ? nruns : RMAX;
        for (int r = tid >> 7; r < ntab; r += 2){
            uint32_t v = tab[r*TP + c];
            uint32_t* dst = &agg[(size_t)run_dst_s[r]*HID + c];
            if (r == 0 || r == nruns-1 || nruns > RMAX) atomicMax(dst, v);
            else *dst = v;
        }
    }
}

// -------- fused layer-0 global nn + layer-1 A (512 thr, 128-row tiles) --------
// out0 = relu(agg@G1 + c1')@G2 + c2 ; A1 = out0@W1a1 + B1 + b1_1 ; agg re-init.
__launch_bounds__(512, 4)
__global__ void k_gnn_ab(uint32_t* __restrict__ agg,
                         const _Float16* __restrict__ g1T, const _Float16* __restrict__ g2T,
                         const float* __restrict__ c1p, const float* __restrict__ gb2,
                         const _Float16* __restrict__ w1aT1, const _Float16* __restrict__ Bh1,
                         const float* __restrict__ lb1_1,
                         _Float16* __restrict__ Ah){
    __shared__ _Float16 Ts[128*LP];
    __shared__ _Float16 Ws[128*128];
    __shared__ float c1s[128];
    __shared__ float c2s[128];
    __shared__ float b1s[128];
    const int tid = threadIdx.x;
    const int node0 = blockIdx.x * 128;
    const int wv = tid >> 6, lane = tid & 63, lq = lane & 15, quad = lane >> 4;
    if (tid < 128){ c1s[tid] = c1p[tid]; c2s[tid] = gb2[tid]; b1s[tid] = lb1_1[tid]; }

    {   // decode agg -> Ts (+re-init), chunk-linear coalesced (4096 uint4 / 512)
        const uint4 vneg = make_uint4(ENC_NEG, ENC_NEG, ENC_NEG, ENC_NEG);
        #pragma unroll
        for (int i = 0; i < 8; i++){
            int chunk = tid + i*512;
            int row = chunk >> 5, qc = chunk & 31;
            uint4* ga = (uint4*)(agg + (size_t)(node0 + row)*HID + qc*4);
            uint4 u = *ga; *ga = vneg;
            uint2 o; o.x = pkh(decf(u.x), decf(u.y)); o.y = pkh(decf(u.z), decf(u.w));
            *(uint2*)(Ts + row*LP + qc*4) = o;
        }
    }
    dma_w8(g1T, Ws, wv, lane);
    __syncthreads();                                   // bar1

    f32x4 acc[8];
    zero_acc8(acc);
    gemm_w(Ts, Ws, acc, wv, lq, quad);                 // agg @ G1
    __syncthreads();                                   // bar2: Ts+Ws readers done
    dma_w8(g2T, Ws, wv, lane);
    #pragma unroll
    for (int ct = 0; ct < 8; ct++)
        #pragma unroll
        for (int rg = 0; rg < 4; rg++){
            int c = ct*16 + lq;
            Ts[(wv*16 + quad*4 + rg)*LP + c] = (_Float16)fmaxf(acc[ct][rg] + c1s[c], 0.f);
        }
    __syncthreads();                                   // bar3

    zero_acc8(acc);
    gemm_w(Ts, Ws, acc, wv, lq, quad);                 // P @ G2
    __syncthreads();                                   // bar4
    dma_w8(w1aT1, Ws, wv, lane);
    #pragma unroll
    for (int ct = 0; ct < 8; ct++)
        #pragma unroll
        for (int rg = 0; rg < 4; rg++){
            int c = ct*16 + lq;
            Ts[(wv*16 + quad*4 + rg)*LP + c] = (_Float16)(acc[ct][rg] + c2s[c]);
        }
    __syncthreads();                                   // bar5

    // prefetch Bh1 residual into regs (latency hidden under GEMM3)
    _Float16 bres[8][4];
    #pragma unroll
    for (int ct = 0; ct < 8; ct++)
        #pragma unroll
        for (int rg = 0; rg < 4; rg++)
            bres[ct][rg] = Bh1[(size_t)(node0 + wv*16 + quad*4 + rg)*HID + ct*16 + lq];

    zero_acc8(acc);
    gemm_w(Ts, Ws, acc, wv, lq, quad);                 // out0 @ W1a1

    #pragma unroll
    for (int ct = 0; ct < 8; ct++)
        #pragma unroll
        for (int rg = 0; rg < 4; rg++){
            int c = ct*16 + lq;
            float v = acc[ct][rg] + (float)bres[ct][rg] + b1s[c];
            Ah[(size_t)(node0 + wv*16 + quad*4 + rg)*HID + c] = (_Float16)v;
        }
}

// -------- final global nn (512 thr, 128-row tiles): relu(agg@G1+c1')@G2 + c2 ----
__launch_bounds__(512, 4)
__global__ void k_gnn(const uint32_t* __restrict__ agg,
                      const _Float16* __restrict__ g1T, const _Float16* __restrict__ g2T,
                      const float* __restrict__ c1p, const float* __restrict__ gb2,
                      float* __restrict__ outf){
    __shared__ _Float16 Ts[128*LP];
    __shared__ _Float16 Ws[128*128];
    __shared__ float c1s[128];
    __shared__ float c2s[128];
    const int tid = threadIdx.x;
    const int node0 = blockIdx.x * 128;
    const int wv = tid >> 6, lane = tid & 63, lq = lane & 15, quad = lane >> 4;
    if (tid < 128){ c1s[tid] = c1p[tid]; c2s[tid] = gb2[tid]; }

    {   // decode agg -> Ts, chunk-linear coalesced
        #pragma unroll
        for (int i = 0; i < 8; i++){
            int chunk = tid + i*512;
            int row = chunk >> 5, qc = chunk & 31;
            const uint4* ga = (const uint4*)(agg + (size_t)(node0 + row)*HID + qc*4);
            uint4 u = *ga;
            uint2 o; o.x = pkh(decf(u.x), decf(u.y)); o.y = pkh(decf(u.z), decf(u.w));
            *(uint2*)(Ts + row*LP + qc*4) = o;
        }
    }
    dma_w8(g1T, Ws, wv, lane);
    __syncthreads();                                   // bar1

    f32x4 acc[8];
    zero_acc8(acc);
    gemm_w(Ts, Ws, acc, wv, lq, quad);                 // agg @ G1
    __syncthreads();                                   // bar2
    dma_w8(g2T, Ws, wv, lane);
    #pragma unroll
    for (int ct = 0; ct < 8; ct++)
        #pragma unroll
        for (int rg = 0; rg < 4; rg++){
            int c = ct*16 + lq;
            Ts[(wv*16 + quad*4 + rg)*LP + c] = (_Float16)fmaxf(acc[ct][rg] + c1s[c], 0.f);
        }
    __syncthreads();                                   // bar3

    zero_acc8(acc);
    gemm_w(Ts, Ws, acc, wv, lq, quad);                 // P @ G2

    #pragma unroll
    for (int ct = 0; ct < 8; ct++)
        #pragma unroll
        for (int rg = 0; rg < 4; rg++){
            int c = ct*16 + lq;
            outf[(size_t)(node0 + wv*16 + quad*4 + rg)*HID + c] = acc[ct][rg] + c2s[c];
        }
}

extern "C" void kernel_launch(void* const* d_in, const int* in_sizes, int n_in,
                              void* d_out, int out_size, void* d_ws, size_t ws_size,
                              hipStream_t stream){
    const float* x   = (const float*)d_in[0];
    const float* pos = (const float*)d_in[1];
    const int*   ei  = (const int*)d_in[2];
    const float* W[16];
    for (int i = 0; i < 16; i++) W[i] = (const float*)d_in[3 + i];
    // per layer l: lw1=W[8l+0] lb1=+1 lw2=+2 lb2=+3 gw1=+4 gb1=+5 gw2=+6 gb2=+7

    uint8_t* p = (uint8_t*)d_ws;
    _Float16* wT[10];
    for (int i = 0; i < 10; i++) wT[i] = (_Float16*)(p + (size_t)i * 32768);
    size_t off = 10 * 32768;
    _Float16* Ah  = (_Float16*)(p + off); off += (size_t)NN * HID * 2;
    _Float16* Bh0 = (_Float16*)(p + off); off += (size_t)NN * HID * 2;
    _Float16* Bh1 = (_Float16*)(p + off); off += (size_t)NN * HID * 2;
    uint32_t* agg = (uint32_t*)(p + off); off += (size_t)NN * HID * 4;
    uint32_t* cnt = (uint32_t*)(p + off); off += (size_t)NN * 4;
    uint32_t* cur = (uint32_t*)(p + off); off += (size_t)NN * 4;
    uint32_t* bsum = (uint32_t*)(p + off); off += 256 * 4;
    float* c1p = (float*)(p + off); off += 256 * 4;
    uint32_t* rank = (uint32_t*)(p + off); off += (size_t)NE * 4;
    uint32_t* sedge = (uint32_t*)(p + off); off += (size_t)E2 * 4;
    (void)ws_size; (void)in_sizes; (void)n_in; (void)out_size;

    // weight transpose slots per layer: W1a^T, W1b^T, W2^T, G1^T, G2^T
    WT wt;
    for (int l = 0; l < 2; l++){
        wt.s[5*l + 0] = W[8*l + 0];
        wt.s[5*l + 1] = W[8*l + 0] + 128*128;
        wt.s[5*l + 2] = W[8*l + 2];
        wt.s[5*l + 3] = W[8*l + 4];
        wt.s[5*l + 4] = W[8*l + 6];
        for (int j = 0; j < 5; j++) wt.d[5*l + j] = wT[5*l + j];
    }
    k_prep<<<268, 256, 0, stream>>>(wt, cnt, W[3], W[4], W[5], W[11], W[12], W[13], c1p);

    // fused: layer-0 A/B GEMMs (blocks 0-511) + edge histogram w/ rank (512-2559)
    k_histab3<<<512 + NE/512, 512, 0, stream>>>(ei, cnt, rank, x, pos,
                                                wT[0], wT[1], wT[6], W[1],
                                                Ah, Bh0, Bh1, agg);
    k_scan1<<<256, 256, 0, stream>>>(cnt, bsum);
    k_scan23<<<256, 256, 0, stream>>>(cnt, bsum, cur);
    k_scatter<<<E2/512, 512, 0, stream>>>(ei, cur, rank, sedge);

    k_edge<<<E2/128, 256, 0, stream>>>(sedge, Ah, Bh0, wT[2], agg);
    k_gnn_ab<<<NN/128, 512, 0, stream>>>(agg, wT[3], wT[4], c1p, W[7],
                                         wT[5], Bh1, W[9], Ah);
    k_edge<<<E2/128, 256, 0, stream>>>(sedge, Ah, Bh1, wT[7], agg);
    k_gnn<<<NN/128, 512, 0, stream>>>(agg, wT[8], wT[9], c1p + 128, W[15],
                                      (float*)d_out);
}